// Round 9
// baseline (862.126 us; speedup 1.0000x reference)
//
#include <hip/hip_runtime.h>
#include <math.h>

typedef unsigned short u16;
typedef unsigned int   u32;

#define DI __device__ __forceinline__

DI float b2f(u16 v){ return __uint_as_float(((u32)v) << 16); }
DI u16 f2b(float f){
  u32 u = __float_as_uint(f);
  u32 r = (u + 0x7fffu + ((u >> 16) & 1u)) >> 16;
  return (u16)r;
}
DI float gelu_exact(float x){ return x * 0.5f * (1.0f + erff(x * 0.70710678118654752f)); }

// Shapes: Bb=4, A=7, C=32, H=W=32, E=128, HEADS=4, d=32, L=N=224, K_tok=7168, HID=85
// x_lf flat: [196][32][32][32] f32, img=(b*49+u*7+v), elem = img*32768 + c*1024 + h*32 + w
// branch 0 (h): token l=(u,h), reduce k=(c, n=(v,w))
// branch 1 (v): token l=(v,w), reduce k=(c, n=(u,h))
//
// Workspace (32.23 MB; ws >= 52.6 MB proven in R3):
//   x2   (bf16) [0, 25690112)               K7 -> end (in-place K8)
//   xq   (f32)  [25690112, +917504)         K0 zero, K1 atomic, K3 read; ALIASED by ao (K6->K7)
//   qkvp (f32)  [26607616, +2752512)        K3->K4; ALIASED by qkvn (K5->K6)
//   qkvd (f32)  [29360128, +2752512)        K4->K5
//   gmax (f32)  [32112640, +50176)
//   gate (f32)  [32162816, +25088)
//   poT  (f32)  [32187904, +43520)          k8_prep -> k8 (po transposed, [br][85][32])

// ---------------- K0: zero xq ----------------
__global__ __launch_bounds__(256) void k0_zero(float* __restrict__ xq)
{
  int idx = blockIdx.x * 256 + threadIdx.x;
  if (idx < 229376) xq[idx] = 0.f;
}

// ---------------- K1: token GEMM, atomic accumulate into xq[br][b][e][l] ----------------
__global__ __launch_bounds__(256) void k1_tok(const float* __restrict__ xlf,
    const float* __restrict__ linw0, const float* __restrict__ linw1,
    float* __restrict__ xq)
{
  __shared__ float As[32][33];
  __shared__ float Ws[128][33];
  const int ks = blockIdx.x;      // 0..7 k-slice
  const int mt = blockIdx.y;      // 0..27 m-tile
  const int br = blockIdx.z;
  const float* linw = br ? linw1 : linw0;
  const int tid = threadIdx.x;
  const int m0 = mt * 32;
  const int b  = m0 / 224;        // tile never crosses b (224 = 7*32)
  const int l0 = m0 % 224;
  const int te = tid >> 3, tm = tid & 7;
  float acc[4][4] = {};
  for (int kc = 0; kc < 28; ++kc) {
    const int kbase = ks * 896 + kc * 32;
    const int c  = kbase / 224;
    const int nb = kbase % 224;   // multiple of 32
    #pragma unroll
    for (int r = 0; r < 4; ++r) {
      int idx = tid + 256 * r;
      int ml, kl;
      if (br == 0) { ml = idx >> 5; kl = idx & 31; }
      else         { ml = idx & 31; kl = idx >> 5; }
      int l = l0 + ml, n = nb + kl;
      int u, h, v2, w2;
      if (br == 0) { u = l >> 5; h = l & 31; v2 = n >> 5; w2 = n & 31; }
      else         { v2 = l >> 5; w2 = l & 31; u = n >> 5; h = n & 31; }
      As[ml][kl] = xlf[(b * 49 + u * 7 + v2) * 32768 + c * 1024 + h * 32 + w2];
    }
    #pragma unroll
    for (int r = 0; r < 16; ++r) {
      int idx = tid + 256 * r;
      int e = idx >> 5, kl = idx & 31;
      Ws[e][kl] = linw[e * 7168 + kbase + kl];
    }
    __syncthreads();
    for (int k = 0; k < 32; ++k) {
      float a[4], wv[4];
      #pragma unroll
      for (int i = 0; i < 4; ++i) a[i] = As[tm * 4 + i][k];
      #pragma unroll
      for (int j = 0; j < 4; ++j) wv[j] = Ws[te * 4 + j][k];
      #pragma unroll
      for (int i = 0; i < 4; ++i)
        #pragma unroll
        for (int j = 0; j < 4; ++j) acc[i][j] += a[i] * wv[j];
    }
    __syncthreads();
  }
  #pragma unroll
  for (int i = 0; i < 4; ++i)
    #pragma unroll
    for (int j = 0; j < 4; ++j)
      atomicAdd(&xq[((br * 4 + b) * 128 + te * 4 + j) * 224 + l0 + tm * 4 + i], acc[i][j]);
}

// ---------------- K3: LN(E) + qkv 1x1 -> qkvp[br][b][384][224] ----------------
__global__ __launch_bounds__(256) void k3_lnqkv(const float* __restrict__ xq,
    const float* __restrict__ g0, const float* __restrict__ b0,
    const float* __restrict__ g1, const float* __restrict__ b1,
    const float* __restrict__ qw0, const float* __restrict__ qw1,
    float* __restrict__ qkvp)
{
  __shared__ float xn[8][129];
  const int lc = blockIdx.x;     // 0..27
  const int b = blockIdx.y, br = blockIdx.z;
  const float* lg = br ? g1 : g0;
  const float* lb = br ? b1 : b0;
  const float* qw = br ? qw1 : qw0;
  const int tid = threadIdx.x;
  const int tl = tid >> 5, lane = tid & 31;
  const int l = lc * 8 + tl;
  const float* xp = xq + ((br * 4 + b) * 128) * 224 + l;
  float v[4]; float s = 0.f, s2 = 0.f;
  #pragma unroll
  for (int i = 0; i < 4; ++i) { v[i] = xp[(lane + 32 * i) * 224]; s += v[i]; s2 += v[i] * v[i]; }
  #pragma unroll
  for (int m = 16; m >= 1; m >>= 1) { s += __shfl_xor(s, m); s2 += __shfl_xor(s2, m); }
  float mean = s * (1.f / 128.f);
  float var  = s2 * (1.f / 128.f) - mean * mean;
  float rs   = rsqrtf(fmaxf(var, 0.f) + 1e-6f);
  #pragma unroll
  for (int i = 0; i < 4; ++i) {
    int c = lane + 32 * i;
    xn[tl][c] = (v[i] - mean) * rs * lg[c] + lb[c];
  }
  __syncthreads();
  for (int jj = 0; jj < 12; ++jj) {
    int idx = tid + 256 * jj;
    int o = idx >> 3, li = idx & 7;
    const float* wr = qw + o * 128;
    float a = 0.f;
    for (int c2 = 0; c2 < 128; ++c2) a += wr[c2] * xn[li][c2];
    qkvp[((br * 4 + b) * 384 + o) * 224 + lc * 8 + li] = a;
  }
}

// ---------------- K4: depthwise 3x3 over (7,32) ----------------
__global__ __launch_bounds__(256) void k4_dw(const float* __restrict__ qkvp,
    const float* __restrict__ dw0, const float* __restrict__ dw1, float* __restrict__ qkvd)
{
  int idx = blockIdx.x * 256 + threadIdx.x;  // 688128
  int l = idx % 224; int r0 = idx / 224;     // r0 = (br*4+b)*384 + o
  int o = r0 % 384;
  int br = (r0 / 384) >> 2;
  const float* dww = (br ? dw1 : dw0) + o * 9;
  int v = l >> 5, w = l & 31;
  const float* src = qkvp + r0 * 224;
  float acc = 0.f;
  #pragma unroll
  for (int dy = -1; dy <= 1; ++dy) {
    int vv = v + dy; if (vv < 0 || vv > 6) continue;
    #pragma unroll
    for (int dx = -1; dx <= 1; ++dx) {
      int ww = w + dx; if (ww < 0 || ww > 31) continue;
      acc += src[vv * 32 + ww] * dww[(dy + 1) * 3 + (dx + 1)];
    }
  }
  qkvd[idx] = acc;
}

// ---------------- K5: head split + l2norm(q,k) -> qkvn[bb][sel][h][l][d] ----------------
__global__ __launch_bounds__(256) void k5_heads(const float* __restrict__ qkvd, float* __restrict__ qkvn)
{
  __shared__ float ts[32][225];
  __shared__ float scs[224];
  const int bid = blockIdx.x;          // bb*12 + sel*4 + h, 96 blocks
  const int h = bid & 3;
  const int sel = (bid >> 2) % 3;
  const int bb = bid / 12;
  const int tid = threadIdx.x;
  const float* src = qkvd + (bb * 384 + sel * 128 + h * 32) * 224;
  for (int r = 0; r < 28; ++r) {
    int idx = tid + 256 * r;
    int d = idx / 224, l = idx % 224;
    ts[d][l] = src[d * 224 + l];
  }
  __syncthreads();
  if (tid < 224) {
    float ss = 0.f;
    for (int d = 0; d < 32; ++d) { float x = ts[d][tid]; ss += x * x; }
    scs[tid] = (sel < 2) ? (1.0f / fmaxf(sqrtf(ss), 1e-12f)) : 1.0f;
  }
  __syncthreads();
  float* dst = qkvn + ((bb * 3 + sel) * 4 + h) * 7168;
  for (int r = 0; r < 28; ++r) {
    int idx = tid + 256 * r;
    int d = idx & 31, l = idx >> 5;
    dst[l * 32 + d] = ts[d][l] * scs[l];
  }
}

// ---------------- K6: fused attention -> ao[bb][e][l] ----------------
__global__ __launch_bounds__(256) void k6_attn(const float* __restrict__ qkvn,
    const float* __restrict__ tmp0, const float* __restrict__ tmp1,
    const float* __restrict__ ca0,  const float* __restrict__ ca1,
    float* __restrict__ ao)
{
  __shared__ float qs[32][33];      // (h*8+i, d)
  __shared__ float ks[128][33];     // (h*32+jj, d)
  __shared__ float sS[32 * 228];    // (h*8+i)*228 + j
  __shared__ float mxs[32], rss[32];
  __shared__ float caf[32], tpf[4];
  const int it = blockIdx.x;        // 0..27 i-tile
  const int b = blockIdx.y, br = blockIdx.z;
  const int bb = br * 4 + b;
  const int tid = threadIdx.x;
  const float* tw = br ? tmp1 : tmp0;
  const float* cw = br ? ca1 : ca0;
  if (tid < 32) caf[tid] = cw[tid];
  if (tid < 4)  tpf[tid] = tw[tid];
  const int i0 = it * 8;
  const float* qb = qkvn + (bb * 3 + 0) * 4 * 7168;
  const float* kb = qkvn + (bb * 3 + 1) * 4 * 7168;
  const float* vb = qkvn + (bb * 3 + 2) * 4 * 7168;
  #pragma unroll
  for (int r = 0; r < 4; ++r) {
    int idx = tid + 256 * r;
    int d = idx & 31, i = (idx >> 5) & 7, h = idx >> 8;
    qs[h * 8 + i][d] = qb[h * 7168 + (i0 + i) * 32 + d];
  }
  const int hC = tid >> 6, iC = (tid >> 3) & 7, jq = tid & 7;
  for (int jt = 0; jt < 7; ++jt) {
    __syncthreads();
    #pragma unroll
    for (int r = 0; r < 16; ++r) {
      int idx = tid + 256 * r;
      int d = idx & 31, jj = (idx >> 5) & 31, h = idx >> 10;
      ks[h * 32 + jj][d] = kb[h * 7168 + (jt * 32 + jj) * 32 + d];
    }
    __syncthreads();
    float a4[4] = {0.f, 0.f, 0.f, 0.f};
    for (int d = 0; d < 32; ++d) {
      float qv = qs[hC * 8 + iC][d];
      #pragma unroll
      for (int r = 0; r < 4; ++r) a4[r] += qv * ks[hC * 32 + jq + 8 * r][d];
    }
    #pragma unroll
    for (int r = 0; r < 4; ++r)
      sS[(hC * 8 + iC) * 228 + jt * 32 + jq + 8 * r] = a4[r] * tpf[hC];
  }
  __syncthreads();
  { // softmax stats per row
    int p = tid & 7, row = tid >> 3;
    float mx = -1e30f;
    for (int q = 0; q < 28; ++q) mx = fmaxf(mx, sS[row * 228 + p + 8 * q]);
    #pragma unroll
    for (int m = 4; m >= 1; m >>= 1) mx = fmaxf(mx, __shfl_xor(mx, m));
    float es = 0.f;
    for (int q = 0; q < 28; ++q) es += expf(sS[row * 228 + p + 8 * q] - mx);
    #pragma unroll
    for (int m = 4; m >= 1; m >>= 1) es += __shfl_xor(es, m);
    if (p == 0) { mxs[row] = mx; rss[row] = 1.0f / es; }
  }
  __syncthreads();
  // attn = softmax*(1+scale)+shift, in place over sS
  for (int q = 0; q < 7; ++q) {
    int pr = tid + 256 * q;
    int i = pr / 224, j = pr % 224;
    float a1[4];
    #pragma unroll
    for (int hh = 0; hh < 4; ++hh) {
      float sv = sS[(hh * 8 + i) * 228 + j];
      float z = fmaxf(sv, 0.f); float z2 = z * z;
      a1[hh] = gelu_exact(z2) * z2;
    }
    #pragma unroll
    for (int hh = 0; hh < 4; ++hh) {
      float sc = 0.f, sh = 0.f;
      #pragma unroll
      for (int k2 = 0; k2 < 4; ++k2) { sc += caf[hh * 4 + k2] * a1[k2]; sh += caf[(hh + 4) * 4 + k2] * a1[k2]; }
      int row = hh * 8 + i;
      float at = expf(sS[row * 228 + j] - mxs[row]) * rss[row];
      sS[row * 228 + j] = at * (1.f + sc) + sh;
    }
  }
  __syncthreads();
  { // PV
    int d = tid & 31, rg = tid >> 5;
    float acc[4] = {0.f, 0.f, 0.f, 0.f};
    for (int j = 0; j < 224; ++j) {
      #pragma unroll
      for (int hh = 0; hh < 4; ++hh)
        acc[hh] += sS[(hh * 8 + rg) * 228 + j] * vb[hh * 7168 + j * 32 + d];
    }
    #pragma unroll
    for (int hh = 0; hh < 4; ++hh)
      ao[(bb * 128 + hh * 32 + d) * 224 + i0 + rg] = acc[hh];
  }
}

// ---------------- K7: proj GEMM + x_res residual -> x2[br][bn][c][l] (bf16) ----------------
__global__ __launch_bounds__(256) void k7_proj(const float* __restrict__ ao,
    const float* __restrict__ pw0, const float* __restrict__ pw1,
    const float* __restrict__ xlf, u16* __restrict__ x2)
{
  __shared__ float Xs[32][225];
  __shared__ float Ws[56][33];
  const int tt = blockIdx.x;          // 0..127: c = tt>>2, n0 = (tt&3)*56
  const int b = blockIdx.y, br = blockIdx.z;
  const int c = tt >> 2;
  const int n0 = (tt & 3) * 56;
  const float* pw = br ? pw1 : pw0;
  const int tid = threadIdx.x;
  const int tl = tid & 31, tn = tid >> 5;
  float acc[7][7] = {};
  const float* xsrc = ao + (br * 4 + b) * 128 * 224;
  for (int ec = 0; ec < 4; ++ec) {
    __syncthreads();
    for (int r = 0; r < 28; ++r) {
      int idx = tid + 256 * r;
      int ee = idx / 224, l = idx % 224;
      Xs[ee][l] = xsrc[(ec * 32 + ee) * 224 + l];
    }
    #pragma unroll
    for (int r = 0; r < 7; ++r) {
      int idx = tid + 256 * r;
      int nn = idx >> 5, ee = idx & 31;
      Ws[nn][ee] = pw[(c * 224 + n0 + nn) * 128 + ec * 32 + ee];
    }
    __syncthreads();
    for (int ee = 0; ee < 32; ++ee) {
      float xv[7], wv[7];
      #pragma unroll
      for (int q = 0; q < 7; ++q) xv[q] = Xs[ee][tl + 32 * q];
      #pragma unroll
      for (int p = 0; p < 7; ++p) wv[p] = Ws[tn + 8 * p][ee];
      #pragma unroll
      for (int p = 0; p < 7; ++p)
        #pragma unroll
        for (int q = 0; q < 7; ++q) acc[p][q] += wv[p] * xv[q];
    }
  }
  #pragma unroll
  for (int p = 0; p < 7; ++p) {
    int n = n0 + tn + 8 * p;
    #pragma unroll
    for (int q = 0; q < 7; ++q) {
      int l = tl + 32 * q;
      int img, off;
      if (br == 0) { img = b * 49 + (l >> 5) * 7 + (n >> 5); off = c * 1024 + (l & 31) * 32 + (n & 31); }
      else         { img = b * 49 + (n >> 5) * 7 + (l >> 5); off = c * 1024 + (n & 31) * 32 + (l & 31); }
      float res = xlf[img * 32768 + off];
      x2[((br * 896 + b * 224 + n) * 32 + c) * 224 + l] = f2b(acc[p][q] + res);
    }
  }
}

// ---------------- k8_prep: transpose po -> poT[br][85][32] ----------------
__global__ __launch_bounds__(256) void k8_prep(const float* __restrict__ po0,
    const float* __restrict__ po1, float* __restrict__ poT)
{
  int idx = blockIdx.x * 256 + threadIdx.x;   // 5440 = 2*85*32
  if (idx >= 5440) return;
  int cc = idx & 31;
  int row = (idx >> 5) % 85;
  int br = idx / (85 * 32);
  const float* po = br ? po1 : po0;
  poT[idx] = po[cc * 85 + row];
}

// ---------------- K8: LN(C)+pin+dw3x3+gelu gate+pout+residual (in place on bf16 x2) ----------------
// R9: LATENCY-CHAIN FIX. R7/R8's unroll-1 r-loops serialize one s_load->lgkmcnt->FMA
// chain per iteration (~250cyc wait vs ~130-260cyc work -> ~30% duty, matches
// VALUBusy 34%). R6's full unroll fixed this but died of icache (~100KB). Middle
// ground: unroll 4 -> 4 iterations' weight loads batched, one wait per 4 iters,
// code ~12-16KB (fits 32KB L1I). Numerics identical.
__global__ __launch_bounds__(256) void k8_mlp(u16* x2,
    const float* __restrict__ lg0, const float* __restrict__ lb0,
    const float* __restrict__ lg1, const float* __restrict__ lb1,
    const float* __restrict__ pin0, const float* __restrict__ pin1,
    const float* __restrict__ dwa0, const float* __restrict__ dwa1,
    const float* __restrict__ poT)
{
  __shared__ float2 ts[9][224];    // (t1, tg) interleaved
  const int img = blockIdx.x;      // 0..895
  const int br = blockIdx.y;
  const float* lg  = br ? lg1 : lg0;
  const float* lb  = br ? lb1 : lb0;
  const float* pin = br ? pin1 : pin0;
  const float* dww = br ? dwa1 : dwa0;
  const float* poB = poT + br * 85 * 32;
  const int tid = threadIdx.x;
  u16* src = x2 + (br * 896 + img) * 7168;
  const int l = tid;
  const int v = l >> 5, w = l & 31;
  float xr[32];
  float acc[32];
  #pragma unroll
  for (int i = 0; i < 32; ++i) acc[i] = 0.f;
  if (l < 224) {
    #pragma unroll
    for (int cc = 0; cc < 32; ++cc) xr[cc] = b2f(src[cc * 224 + l]);
    float s = 0.f, s2 = 0.f;
    #pragma unroll
    for (int cc = 0; cc < 32; ++cc) { s += xr[cc]; s2 += xr[cc] * xr[cc]; }
    float mean = s * (1.f / 32.f);
    float var  = s2 * (1.f / 32.f) - mean * mean;
    float rs   = rsqrtf(fmaxf(var, 0.f) + 1e-6f);
    #pragma unroll
    for (int cc = 0; cc < 32; ++cc)
      xr[cc] = (xr[cc] - mean) * rs * lg[cc] + lb[cc];
  }
  #pragma unroll 1
  for (int ch = 0; ch < 10; ++ch) {
    const int c0 = ch * 9;
    const int sz = (c0 + 9 <= 85) ? 9 : (85 - c0);   // 9,...,9,4
    if (l < 224) {
      #pragma unroll 4
      for (int r = 0; r < sz; ++r) {
        const float* p1 = pin + (c0 + r) * 32;
        const float* p2 = pin + (c0 + r + 85) * 32;
        float a1 = 0.f, a2 = 0.f;
        #pragma unroll
        for (int cc = 0; cc < 32; ++cc) { a1 += p1[cc] * xr[cc]; a2 += p2[cc] * xr[cc]; }
        ts[r][l] = make_float2(a1, a2);
      }
    }
    __syncthreads();
    if (l < 224) {
      #pragma unroll 4
      for (int r = 0; r < sz; ++r) {
        const float* w1 = dww + (c0 + r) * 9;
        const float* w2 = dww + (c0 + r + 85) * 9;
        float d1 = 0.f, d2 = 0.f;
        #pragma unroll
        for (int dy = -1; dy <= 1; ++dy) {
          int vv = v + dy; if (vv < 0 || vv > 6) continue;
          #pragma unroll
          for (int dx = -1; dx <= 1; ++dx) {
            int ww = w + dx; if (ww < 0 || ww > 31) continue;
            float2 t = ts[r][vv * 32 + ww];
            int wi = (dy + 1) * 3 + dx + 1;
            d1 += t.x * w1[wi];
            d2 += t.y * w2[wi];
          }
        }
        float gr = gelu_exact(d1) * d2;
        const float* pr = poB + (c0 + r) * 32;   // contiguous 32 floats
        #pragma unroll
        for (int cc = 0; cc < 32; ++cc) acc[cc] += pr[cc] * gr;
      }
    }
    __syncthreads();
  }
  if (l < 224) {
    #pragma unroll
    for (int cc = 0; cc < 32; ++cc) {
      int o = cc * 224 + l;
      src[o] = f2b(b2f(src[o]) + acc[cc]);
    }
  }
}

// ---------------- K9a: adaptive max pool per (t, c64) ----------------
__global__ __launch_bounds__(256) void k9_pool(const u16* __restrict__ x3, float* __restrict__ gmax)
{
  __shared__ float red[4];
  const int bid = blockIdx.x;      // t*64 + c64
  const int c64 = bid & 63;
  const int t = bid >> 6;
  const int c = c64 & 31, which = c64 >> 5;
  const int b = t / 49; const int uv = t % 49; const int u = uv / 7; const int vq = uv % 7;
  const int tid = threadIdx.x;
  float mx = -1e30f;
  if (which == 0) {
    int h = tid & 31, w0 = tid >> 5;
    #pragma unroll
    for (int r = 0; r < 4; ++r) {
      int w = w0 + 8 * r;
      mx = fmaxf(mx, b2f(x3[((b * 224 + vq * 32 + w) * 32 + c) * 224 + u * 32 + h]));
    }
  } else {
    int w = tid & 31, h0 = tid >> 5;
    #pragma unroll
    for (int r = 0; r < 4; ++r) {
      int h = h0 + 8 * r;
      mx = fmaxf(mx, b2f(x3[((896 + b * 224 + u * 32 + h) * 32 + c) * 224 + vq * 32 + w]));
    }
  }
  #pragma unroll
  for (int m = 32; m >= 1; m >>= 1) mx = fmaxf(mx, __shfl_xor(mx, m));
  if ((tid & 63) == 0) red[tid >> 6] = mx;
  __syncthreads();
  if (tid == 0)
    gmax[t * 64 + c64] = fmaxf(fmaxf(red[0], red[1]), fmaxf(red[2], red[3]));
}

// ---------------- K9b: FC gate ----------------
__global__ __launch_bounds__(256) void k9_fc(const float* __restrict__ gmax,
    const float* __restrict__ f1, const float* __restrict__ f2, float* __restrict__ gate)
{
  int t = blockIdx.x * 256 + threadIdx.x;
  if (t >= 196) return;
  float g1[8];
  #pragma unroll
  for (int o = 0; o < 8; ++o) {
    float a = 0.f;
    #pragma unroll
    for (int c2 = 0; c2 < 64; ++c2) a += f1[o * 64 + c2] * gmax[t * 64 + c2];
    g1[o] = (a >= 0.f) ? a : 0.1f * a;
  }
  #pragma unroll
  for (int c2 = 0; c2 < 32; ++c2) {
    float a = 0.f;
    #pragma unroll
    for (int o = 0; o < 8; ++o) a += f2[c2 * 8 + o] * g1[o];
    gate[t * 32 + c2] = 1.f / (1.f + expf(-a));
  }
}

// ---------------- K9c: gated combine -> out[t][c][h][w] f32 ----------------
__global__ __launch_bounds__(256) void k9_final(const u16* __restrict__ x3,
    const float* __restrict__ gate, float* __restrict__ out)
{
  __shared__ float o1s[32][33];
  const int bid = blockIdx.x;   // t*32 + c
  const int c = bid & 31;
  const int t = bid >> 5;
  const int b = t / 49; const int uv = t % 49; const int u = uv / 7; const int vq = uv % 7;
  const int tid = threadIdx.x;
  const float g = gate[t * 32 + c];
  #pragma unroll
  for (int r = 0; r < 4; ++r) {
    int h = tid & 31; int w = (tid >> 5) + 8 * r;
    o1s[w][h] = b2f(x3[((b * 224 + vq * 32 + w) * 32 + c) * 224 + u * 32 + h]);
  }
  __syncthreads();
  #pragma unroll
  for (int r = 0; r < 4; ++r) {
    int w = tid & 31; int h = (tid >> 5) + 8 * r;
    float o2 = b2f(x3[((896 + b * 224 + u * 32 + h) * 32 + c) * 224 + vq * 32 + w]);
    float o1 = o1s[w][h];
    out[(t * 32 + c) * 1024 + h * 32 + w] = o1 * g + o2 * (1.f - g);
  }
}

extern "C" void kernel_launch(void* const* d_in, const int* in_sizes, int n_in,
                              void* d_out, int out_size, void* d_ws, size_t ws_size,
                              hipStream_t stream)
{
  const float* xlf    = (const float*)d_in[0];
  const float* h_lin  = (const float*)d_in[1];
  const float* h_temp = (const float*)d_in[2];
  const float* h_g1   = (const float*)d_in[3];
  const float* h_b1   = (const float*)d_in[4];
  const float* h_qkv  = (const float*)d_in[5];
  const float* h_qdw  = (const float*)d_in[6];
  const float* h_proj = (const float*)d_in[7];
  const float* h_ca   = (const float*)d_in[8];
  const float* h_ge   = (const float*)d_in[9];
  const float* h_be   = (const float*)d_in[10];
  const float* h_pin  = (const float*)d_in[11];
  const float* h_dw   = (const float*)d_in[12];
  const float* h_po   = (const float*)d_in[13];
  const float* v_lin  = (const float*)d_in[14];
  const float* v_temp = (const float*)d_in[15];
  const float* v_g1   = (const float*)d_in[16];
  const float* v_b1   = (const float*)d_in[17];
  const float* v_qkv  = (const float*)d_in[18];
  const float* v_qdw  = (const float*)d_in[19];
  const float* v_proj = (const float*)d_in[20];
  const float* v_ca   = (const float*)d_in[21];
  const float* v_ge   = (const float*)d_in[22];
  const float* v_be   = (const float*)d_in[23];
  const float* v_pin  = (const float*)d_in[24];
  const float* v_dw   = (const float*)d_in[25];
  const float* v_po   = (const float*)d_in[26];
  const float* f1     = (const float*)d_in[27];
  const float* f2     = (const float*)d_in[28];

  char* w = (char*)d_ws;
  u16*   x2   = (u16*)  (w + 0);          // 25,690,112 B  (bf16 residual stream, in-place K8)
  float* xq   = (float*)(w + 25690112);   //    917,504 B  (aliased by ao after K3)
  float* qkvp = (float*)(w + 26607616);   //  2,752,512 B  (aliased by qkvn after K4)
  float* qkvd = (float*)(w + 29360128);   //  2,752,512 B
  float* gmax = (float*)(w + 32112640);   //     50,176 B
  float* gate = (float*)(w + 32162816);   //     25,088 B
  float* poT  = (float*)(w + 32187904);   //     43,520 B  (k8_prep -> k8)
  float* qkvn = qkvp;                     // K5 writes (qkvp dead)
  float* ao   = xq;                       // K6 writes (xq dead)
  // total ws used: 32,231,424 B (~30.7 MB)

  k0_zero  <<<896, 256, 0, stream>>>(xq);
  k8_prep  <<<22, 256, 0, stream>>>(h_po, v_po, poT);
  k1_tok   <<<dim3(8, 28, 2), 256, 0, stream>>>(xlf, h_lin, v_lin, xq);
  k3_lnqkv <<<dim3(28, 4, 2), 256, 0, stream>>>(xq, h_g1, h_b1, v_g1, v_b1, h_qkv, v_qkv, qkvp);
  k4_dw    <<<2688, 256, 0, stream>>>(qkvp, h_qdw, v_qdw, qkvd);
  k5_heads <<<96, 256, 0, stream>>>(qkvd, qkvn);
  k6_attn  <<<dim3(28, 4, 2), 256, 0, stream>>>(qkvn, h_temp, v_temp, h_ca, v_ca, ao);
  k7_proj  <<<dim3(128, 4, 2), 256, 0, stream>>>(ao, h_proj, v_proj, xlf, x2);
  k8_mlp   <<<dim3(896, 2), 256, 0, stream>>>(x2, h_ge, h_be, v_ge, v_be,
                                              h_pin, v_pin, h_dw, v_dw, poT);
  k9_pool  <<<12544, 256, 0, stream>>>(x2, gmax);
  k9_fc    <<<1, 256, 0, stream>>>(gmax, f1, f2, gate);
  k9_final <<<6272, 256, 0, stream>>>(x2, gate, (float*)d_out);
}

// Round 10
// 816.932 us; speedup vs baseline: 1.0553x; 1.0553x over previous
//
#include <hip/hip_runtime.h>
#include <math.h>

typedef unsigned short u16;
typedef unsigned int   u32;
typedef __attribute__((ext_vector_type(8))) short short8;
typedef __attribute__((ext_vector_type(4))) float float4v;

#define DI __device__ __forceinline__

DI float b2f(u16 v){ return __uint_as_float(((u32)v) << 16); }
DI u16 f2b(float f){
  u32 u = __float_as_uint(f);
  u32 r = (u + 0x7fffu + ((u >> 16) & 1u)) >> 16;
  return (u16)r;
}
DI float gelu_exact(float x){ return x * 0.5f * (1.0f + erff(x * 0.70710678118654752f)); }

// Shapes: Bb=4, A=7, C=32, H=W=32, E=128, HEADS=4, d=32, L=N=224, K_tok=7168, HID=85
// x_lf flat: [196][32][32][32] f32, img=(b*49+u*7+v), elem = img*32768 + c*1024 + h*32 + w
// branch 0 (h): token l=(u,h), reduce k=(c, n=(v,w))
// branch 1 (v): token l=(v,w), reduce k=(c, n=(u,h))
//
// Workspace (35.9 MB; ws >= 52.6 MB proven in R3):
//   x2    (bf16) [0, 25690112)              K7 -> end (in-place K8)
//   xq    (f32)  [25690112, +917504)        K0 zero, K1 atomic, K3 read; ALIASED by ao (K6->K7)
//   qkvp  (f32)  [26607616, +2752512)       K3->K4; ALIASED by qkvn (K5->K6)
//   qkvd  (f32)  [29360128, +2752512)       K4->K5
//   gmax  (f32)  [32112640, +50176)
//   gate  (f32)  [32162816, +25088)
//   poT   (f32)  [32187904, +43520)         k8_prep -> k8 (po transposed, [br][85][32])
//   linwB (bf16) [32231424, +3670016)       k_wprep -> k1 (lin_w in bf16, [br][128][7168])

// ---------------- K0: zero xq ----------------
__global__ __launch_bounds__(256) void k0_zero(float* __restrict__ xq)
{
  int idx = blockIdx.x * 256 + threadIdx.x;
  if (idx < 229376) xq[idx] = 0.f;
}

// ---------------- k_wprep: lin_w f32 -> bf16 [br][128][7168] ----------------
__global__ __launch_bounds__(256) void k_wprep(const float* __restrict__ w0,
    const float* __restrict__ w1, u16* __restrict__ linwB)
{
  int base = blockIdx.x * 1024 + threadIdx.x;   // 1,835,008 total
  #pragma unroll
  for (int r = 0; r < 4; ++r) {
    int i = base + 256 * r;
    if (i < 1835008) {
      const float* src = (i < 917504) ? w0 : w1;
      linwB[i] = f2b(src[i % 917504]);
    }
  }
}

// ---------------- K1 (MFMA): token GEMM, atomic accumulate into xq[bb][e][l] ----------------
// grid: (ks=16, mblk=4, bb=8). Per block: output rows [mblk*64, +64) of 224, K-chunk 448.
// Per wave: one 16-row strip x full E=128 (8 n-tiles), acc 8 x float4.
// A staged 64x32 bf16 (gather from xlf + convert), W staged 128x32 bf16 (from linwB).
__global__ __launch_bounds__(256) void k1_mfma(const float* __restrict__ xlf,
    const u16* __restrict__ linwB, float* __restrict__ xq)
{
  __shared__ u16 Asb[64][40];    // +8 pad: row stride 80B, 16B-aligned
  __shared__ u16 Wsb[128][40];
  const int ks   = blockIdx.x;   // 0..15
  const int mblk = blockIdx.y;   // 0..3
  const int bb   = blockIdx.z;   // br*4+b
  const int br = bb >> 2, b = bb & 3;
  const int tid = threadIdx.x;
  const int wid = tid >> 6, lane = tid & 63;
  const int quad = lane >> 4, r16 = lane & 15;
  const int m0s = mblk * 64 + wid * 16;          // this wave's strip base (global token row)
  const bool active = (m0s < 224);
  const u16* wsrc = linwB + br * 917504;

  float4v acc[8];
  #pragma unroll
  for (int nt = 0; nt < 8; ++nt) acc[nt] = (float4v){0.f, 0.f, 0.f, 0.f};

  #pragma unroll 1
  for (int step = 0; step < 14; ++step) {
    const int k0 = ks * 448 + step * 32;
    const int c   = k0 / 224;
    const int rem = k0 % 224;     // multiple of 32
    // stage A: 64 rows x 32 k
    #pragma unroll
    for (int r = 0; r < 8; ++r) {
      int idx = tid + 256 * r;    // 2048
      int ml = idx >> 5, kl = idx & 31;
      int l = mblk * 64 + ml;
      float val = 0.f;
      if (l < 224) {
        int u, h, v2, w2;
        if (br == 0) { u = l >> 5; h = l & 31; v2 = rem >> 5; w2 = kl; }
        else         { v2 = l >> 5; w2 = l & 31; u = rem >> 5; h = kl; }
        val = xlf[(b * 49 + u * 7 + v2) * 32768 + c * 1024 + h * 32 + w2];
      }
      Asb[ml][kl] = f2b(val);
    }
    // stage W: 128 rows x 32 k
    #pragma unroll
    for (int r = 0; r < 16; ++r) {
      int idx = tid + 256 * r;    // 4096
      int e = idx >> 5, kl = idx & 31;
      Wsb[e][kl] = wsrc[e * 7168 + k0 + kl];
    }
    __syncthreads();
    if (active) {
      short8 af = *(const short8*)&Asb[wid * 16 + r16][quad * 8];
      #pragma unroll
      for (int nt = 0; nt < 8; ++nt) {
        short8 bf = *(const short8*)&Wsb[nt * 16 + r16][quad * 8];
        acc[nt] = __builtin_amdgcn_mfma_f32_16x16x32_bf16(af, bf, acc[nt], 0, 0, 0);
      }
    }
    __syncthreads();
  }
  if (active) {
    #pragma unroll
    for (int nt = 0; nt < 8; ++nt) {
      int e = nt * 16 + r16;
      #pragma unroll
      for (int reg = 0; reg < 4; ++reg) {
        int tok = m0s + quad * 4 + reg;
        atomicAdd(&xq[(bb * 128 + e) * 224 + tok], acc[nt][reg]);
      }
    }
  }
}

// ---------------- K3: LN(E) + qkv 1x1 -> qkvp[br][b][384][224] ----------------
__global__ __launch_bounds__(256) void k3_lnqkv(const float* __restrict__ xq,
    const float* __restrict__ g0, const float* __restrict__ b0,
    const float* __restrict__ g1, const float* __restrict__ b1,
    const float* __restrict__ qw0, const float* __restrict__ qw1,
    float* __restrict__ qkvp)
{
  __shared__ float xn[8][129];
  const int lc = blockIdx.x;     // 0..27
  const int b = blockIdx.y, br = blockIdx.z;
  const float* lg = br ? g1 : g0;
  const float* lb = br ? b1 : b0;
  const float* qw = br ? qw1 : qw0;
  const int tid = threadIdx.x;
  const int tl = tid >> 5, lane = tid & 31;
  const int l = lc * 8 + tl;
  const float* xp = xq + ((br * 4 + b) * 128) * 224 + l;
  float v[4]; float s = 0.f, s2 = 0.f;
  #pragma unroll
  for (int i = 0; i < 4; ++i) { v[i] = xp[(lane + 32 * i) * 224]; s += v[i]; s2 += v[i] * v[i]; }
  #pragma unroll
  for (int m = 16; m >= 1; m >>= 1) { s += __shfl_xor(s, m); s2 += __shfl_xor(s2, m); }
  float mean = s * (1.f / 128.f);
  float var  = s2 * (1.f / 128.f) - mean * mean;
  float rs   = rsqrtf(fmaxf(var, 0.f) + 1e-6f);
  #pragma unroll
  for (int i = 0; i < 4; ++i) {
    int c = lane + 32 * i;
    xn[tl][c] = (v[i] - mean) * rs * lg[c] + lb[c];
  }
  __syncthreads();
  for (int jj = 0; jj < 12; ++jj) {
    int idx = tid + 256 * jj;
    int o = idx >> 3, li = idx & 7;
    const float* wr = qw + o * 128;
    float a = 0.f;
    for (int c2 = 0; c2 < 128; ++c2) a += wr[c2] * xn[li][c2];
    qkvp[((br * 4 + b) * 384 + o) * 224 + lc * 8 + li] = a;
  }
}

// ---------------- K4: depthwise 3x3 over (7,32) ----------------
__global__ __launch_bounds__(256) void k4_dw(const float* __restrict__ qkvp,
    const float* __restrict__ dw0, const float* __restrict__ dw1, float* __restrict__ qkvd)
{
  int idx = blockIdx.x * 256 + threadIdx.x;  // 688128
  int l = idx % 224; int r0 = idx / 224;     // r0 = (br*4+b)*384 + o
  int o = r0 % 384;
  int br = (r0 / 384) >> 2;
  const float* dww = (br ? dw1 : dw0) + o * 9;
  int v = l >> 5, w = l & 31;
  const float* src = qkvp + r0 * 224;
  float acc = 0.f;
  #pragma unroll
  for (int dy = -1; dy <= 1; ++dy) {
    int vv = v + dy; if (vv < 0 || vv > 6) continue;
    #pragma unroll
    for (int dx = -1; dx <= 1; ++dx) {
      int ww = w + dx; if (ww < 0 || ww > 31) continue;
      acc += src[vv * 32 + ww] * dww[(dy + 1) * 3 + (dx + 1)];
    }
  }
  qkvd[idx] = acc;
}

// ---------------- K5: head split + l2norm(q,k) -> qkvn[bb][sel][h][l][d] ----------------
__global__ __launch_bounds__(256) void k5_heads(const float* __restrict__ qkvd, float* __restrict__ qkvn)
{
  __shared__ float ts[32][225];
  __shared__ float scs[224];
  const int bid = blockIdx.x;          // bb*12 + sel*4 + h, 96 blocks
  const int h = bid & 3;
  const int sel = (bid >> 2) % 3;
  const int bb = bid / 12;
  const int tid = threadIdx.x;
  const float* src = qkvd + (bb * 384 + sel * 128 + h * 32) * 224;
  for (int r = 0; r < 28; ++r) {
    int idx = tid + 256 * r;
    int d = idx / 224, l = idx % 224;
    ts[d][l] = src[d * 224 + l];
  }
  __syncthreads();
  if (tid < 224) {
    float ss = 0.f;
    for (int d = 0; d < 32; ++d) { float x = ts[d][tid]; ss += x * x; }
    scs[tid] = (sel < 2) ? (1.0f / fmaxf(sqrtf(ss), 1e-12f)) : 1.0f;
  }
  __syncthreads();
  float* dst = qkvn + ((bb * 3 + sel) * 4 + h) * 7168;
  for (int r = 0; r < 28; ++r) {
    int idx = tid + 256 * r;
    int d = idx & 31, l = idx >> 5;
    dst[l * 32 + d] = ts[d][l] * scs[l];
  }
}

// ---------------- K6: fused attention -> ao[bb][e][l] ----------------
__global__ __launch_bounds__(256) void k6_attn(const float* __restrict__ qkvn,
    const float* __restrict__ tmp0, const float* __restrict__ tmp1,
    const float* __restrict__ ca0,  const float* __restrict__ ca1,
    float* __restrict__ ao)
{
  __shared__ float qs[32][33];      // (h*8+i, d)
  __shared__ float ks[128][33];     // (h*32+jj, d)
  __shared__ float sS[32 * 228];    // (h*8+i)*228 + j
  __shared__ float mxs[32], rss[32];
  __shared__ float caf[32], tpf[4];
  const int it = blockIdx.x;        // 0..27 i-tile
  const int b = blockIdx.y, br = blockIdx.z;
  const int bb = br * 4 + b;
  const int tid = threadIdx.x;
  const float* tw = br ? tmp1 : tmp0;
  const float* cw = br ? ca1 : ca0;
  if (tid < 32) caf[tid] = cw[tid];
  if (tid < 4)  tpf[tid] = tw[tid];
  const int i0 = it * 8;
  const float* qb = qkvn + (bb * 3 + 0) * 4 * 7168;
  const float* kb = qkvn + (bb * 3 + 1) * 4 * 7168;
  const float* vb = qkvn + (bb * 3 + 2) * 4 * 7168;
  #pragma unroll
  for (int r = 0; r < 4; ++r) {
    int idx = tid + 256 * r;
    int d = idx & 31, i = (idx >> 5) & 7, h = idx >> 8;
    qs[h * 8 + i][d] = qb[h * 7168 + (i0 + i) * 32 + d];
  }
  const int hC = tid >> 6, iC = (tid >> 3) & 7, jq = tid & 7;
  for (int jt = 0; jt < 7; ++jt) {
    __syncthreads();
    #pragma unroll
    for (int r = 0; r < 16; ++r) {
      int idx = tid + 256 * r;
      int d = idx & 31, jj = (idx >> 5) & 31, h = idx >> 10;
      ks[h * 32 + jj][d] = kb[h * 7168 + (jt * 32 + jj) * 32 + d];
    }
    __syncthreads();
    float a4[4] = {0.f, 0.f, 0.f, 0.f};
    for (int d = 0; d < 32; ++d) {
      float qv = qs[hC * 8 + iC][d];
      #pragma unroll
      for (int r = 0; r < 4; ++r) a4[r] += qv * ks[hC * 32 + jq + 8 * r][d];
    }
    #pragma unroll
    for (int r = 0; r < 4; ++r)
      sS[(hC * 8 + iC) * 228 + jt * 32 + jq + 8 * r] = a4[r] * tpf[hC];
  }
  __syncthreads();
  { // softmax stats per row
    int p = tid & 7, row = tid >> 3;
    float mx = -1e30f;
    for (int q = 0; q < 28; ++q) mx = fmaxf(mx, sS[row * 228 + p + 8 * q]);
    #pragma unroll
    for (int m = 4; m >= 1; m >>= 1) mx = fmaxf(mx, __shfl_xor(mx, m));
    float es = 0.f;
    for (int q = 0; q < 28; ++q) es += expf(sS[row * 228 + p + 8 * q] - mx);
    #pragma unroll
    for (int m = 4; m >= 1; m >>= 1) es += __shfl_xor(es, m);
    if (p == 0) { mxs[row] = mx; rss[row] = 1.0f / es; }
  }
  __syncthreads();
  // attn = softmax*(1+scale)+shift, in place over sS
  for (int q = 0; q < 7; ++q) {
    int pr = tid + 256 * q;
    int i = pr / 224, j = pr % 224;
    float a1[4];
    #pragma unroll
    for (int hh = 0; hh < 4; ++hh) {
      float sv = sS[(hh * 8 + i) * 228 + j];
      float z = fmaxf(sv, 0.f); float z2 = z * z;
      a1[hh] = gelu_exact(z2) * z2;
    }
    #pragma unroll
    for (int hh = 0; hh < 4; ++hh) {
      float sc = 0.f, sh = 0.f;
      #pragma unroll
      for (int k2 = 0; k2 < 4; ++k2) { sc += caf[hh * 4 + k2] * a1[k2]; sh += caf[(hh + 4) * 4 + k2] * a1[k2]; }
      int row = hh * 8 + i;
      float at = expf(sS[row * 228 + j] - mxs[row]) * rss[row];
      sS[row * 228 + j] = at * (1.f + sc) + sh;
    }
  }
  __syncthreads();
  { // PV
    int d = tid & 31, rg = tid >> 5;
    float acc[4] = {0.f, 0.f, 0.f, 0.f};
    for (int j = 0; j < 224; ++j) {
      #pragma unroll
      for (int hh = 0; hh < 4; ++hh)
        acc[hh] += sS[(hh * 8 + rg) * 228 + j] * vb[hh * 7168 + j * 32 + d];
    }
    #pragma unroll
    for (int hh = 0; hh < 4; ++hh)
      ao[(bb * 128 + hh * 32 + d) * 224 + i0 + rg] = acc[hh];
  }
}

// ---------------- K7: proj GEMM + x_res residual -> x2[br][bn][c][l] (bf16) ----------------
__global__ __launch_bounds__(256) void k7_proj(const float* __restrict__ ao,
    const float* __restrict__ pw0, const float* __restrict__ pw1,
    const float* __restrict__ xlf, u16* __restrict__ x2)
{
  __shared__ float Xs[32][225];
  __shared__ float Ws[56][33];
  const int tt = blockIdx.x;          // 0..127: c = tt>>2, n0 = (tt&3)*56
  const int b = blockIdx.y, br = blockIdx.z;
  const int c = tt >> 2;
  const int n0 = (tt & 3) * 56;
  const float* pw = br ? pw1 : pw0;
  const int tid = threadIdx.x;
  const int tl = tid & 31, tn = tid >> 5;
  float acc[7][7] = {};
  const float* xsrc = ao + (br * 4 + b) * 128 * 224;
  for (int ec = 0; ec < 4; ++ec) {
    __syncthreads();
    for (int r = 0; r < 28; ++r) {
      int idx = tid + 256 * r;
      int ee = idx / 224, l = idx % 224;
      Xs[ee][l] = xsrc[(ec * 32 + ee) * 224 + l];
    }
    #pragma unroll
    for (int r = 0; r < 7; ++r) {
      int idx = tid + 256 * r;
      int nn = idx >> 5, ee = idx & 31;
      Ws[nn][ee] = pw[(c * 224 + n0 + nn) * 128 + ec * 32 + ee];
    }
    __syncthreads();
    for (int ee = 0; ee < 32; ++ee) {
      float xv[7], wv[7];
      #pragma unroll
      for (int q = 0; q < 7; ++q) xv[q] = Xs[ee][tl + 32 * q];
      #pragma unroll
      for (int p = 0; p < 7; ++p) wv[p] = Ws[tn + 8 * p][ee];
      #pragma unroll
      for (int p = 0; p < 7; ++p)
        #pragma unroll
        for (int q = 0; q < 7; ++q) acc[p][q] += wv[p] * xv[q];
    }
  }
  #pragma unroll
  for (int p = 0; p < 7; ++p) {
    int n = n0 + tn + 8 * p;
    #pragma unroll
    for (int q = 0; q < 7; ++q) {
      int l = tl + 32 * q;
      int img, off;
      if (br == 0) { img = b * 49 + (l >> 5) * 7 + (n >> 5); off = c * 1024 + (l & 31) * 32 + (n & 31); }
      else         { img = b * 49 + (n >> 5) * 7 + (l >> 5); off = c * 1024 + (n & 31) * 32 + (l & 31); }
      float res = xlf[img * 32768 + off];
      x2[((br * 896 + b * 224 + n) * 32 + c) * 224 + l] = f2b(acc[p][q] + res);
    }
  }
}

// ---------------- k8_prep: transpose po -> poT[br][85][32] ----------------
__global__ __launch_bounds__(256) void k8_prep(const float* __restrict__ po0,
    const float* __restrict__ po1, float* __restrict__ poT)
{
  int idx = blockIdx.x * 256 + threadIdx.x;   // 5440 = 2*85*32
  if (idx >= 5440) return;
  int cc = idx & 31;
  int row = (idx >> 5) % 85;
  int br = idx / (85 * 32);
  const float* po = br ? po1 : po0;
  poT[idx] = po[cc * 85 + row];
}

// ---------------- K8: LN(C)+pin+dw3x3+gelu gate+pout+residual (R8-exact, best known 378us) ----------------
__global__ __launch_bounds__(256) void k8_mlp(u16* x2,
    const float* __restrict__ lg0, const float* __restrict__ lb0,
    const float* __restrict__ lg1, const float* __restrict__ lb1,
    const float* __restrict__ pin0, const float* __restrict__ pin1,
    const float* __restrict__ dwa0, const float* __restrict__ dwa1,
    const float* __restrict__ poT)
{
  __shared__ float2 ts[9][224];    // (t1, tg) interleaved
  const int img = blockIdx.x;      // 0..895
  const int br = blockIdx.y;
  const float* lg  = br ? lg1 : lg0;
  const float* lb  = br ? lb1 : lb0;
  const float* pin = br ? pin1 : pin0;
  const float* dww = br ? dwa1 : dwa0;
  const float* poB = poT + br * 85 * 32;
  const int tid = threadIdx.x;
  u16* src = x2 + (br * 896 + img) * 7168;
  const int l = tid;
  const int v = l >> 5, w = l & 31;
  float xr[32];
  float acc[32];
  #pragma unroll
  for (int i = 0; i < 32; ++i) acc[i] = 0.f;
  if (l < 224) {
    #pragma unroll
    for (int cc = 0; cc < 32; ++cc) xr[cc] = b2f(src[cc * 224 + l]);
    float s = 0.f, s2 = 0.f;
    #pragma unroll
    for (int cc = 0; cc < 32; ++cc) { s += xr[cc]; s2 += xr[cc] * xr[cc]; }
    float mean = s * (1.f / 32.f);
    float var  = s2 * (1.f / 32.f) - mean * mean;
    float rs   = rsqrtf(fmaxf(var, 0.f) + 1e-6f);
    #pragma unroll
    for (int cc = 0; cc < 32; ++cc)
      xr[cc] = (xr[cc] - mean) * rs * lg[cc] + lb[cc];
  }
  #pragma unroll 1
  for (int ch = 0; ch < 10; ++ch) {
    const int c0 = ch * 9;
    const int sz = (c0 + 9 <= 85) ? 9 : (85 - c0);   // 9,...,9,4
    if (l < 224) {
      #pragma unroll 1
      for (int r = 0; r < sz; ++r) {
        const float* p1 = pin + (c0 + r) * 32;
        const float* p2 = pin + (c0 + r + 85) * 32;
        float a1 = 0.f, a2 = 0.f;
        #pragma unroll
        for (int cc = 0; cc < 32; ++cc) { a1 += p1[cc] * xr[cc]; a2 += p2[cc] * xr[cc]; }
        ts[r][l] = make_float2(a1, a2);
      }
    }
    __syncthreads();
    if (l < 224) {
      #pragma unroll 1
      for (int r = 0; r < sz; ++r) {
        const float* w1 = dww + (c0 + r) * 9;
        const float* w2 = dww + (c0 + r + 85) * 9;
        float d1 = 0.f, d2 = 0.f;
        #pragma unroll
        for (int dy = -1; dy <= 1; ++dy) {
          int vv = v + dy; if (vv < 0 || vv > 6) continue;
          #pragma unroll
          for (int dx = -1; dx <= 1; ++dx) {
            int ww = w + dx; if (ww < 0 || ww > 31) continue;
            float2 t = ts[r][vv * 32 + ww];
            int wi = (dy + 1) * 3 + dx + 1;
            d1 += t.x * w1[wi];
            d2 += t.y * w2[wi];
          }
        }
        float gr = gelu_exact(d1) * d2;
        const float* pr = poB + (c0 + r) * 32;   // contiguous 32 floats
        #pragma unroll
        for (int cc = 0; cc < 32; ++cc) acc[cc] += pr[cc] * gr;
      }
    }
    __syncthreads();
  }
  if (l < 224) {
    #pragma unroll
    for (int cc = 0; cc < 32; ++cc) {
      int o = cc * 224 + l;
      src[o] = f2b(b2f(src[o]) + acc[cc]);
    }
  }
}

// ---------------- K9a: adaptive max pool per (t, c64) ----------------
__global__ __launch_bounds__(256) void k9_pool(const u16* __restrict__ x3, float* __restrict__ gmax)
{
  __shared__ float red[4];
  const int bid = blockIdx.x;      // t*64 + c64
  const int c64 = bid & 63;
  const int t = bid >> 6;
  const int c = c64 & 31, which = c64 >> 5;
  const int b = t / 49; const int uv = t % 49; const int u = uv / 7; const int vq = uv % 7;
  const int tid = threadIdx.x;
  float mx = -1e30f;
  if (which == 0) {
    int h = tid & 31, w0 = tid >> 5;
    #pragma unroll
    for (int r = 0; r < 4; ++r) {
      int w = w0 + 8 * r;
      mx = fmaxf(mx, b2f(x3[((b * 224 + vq * 32 + w) * 32 + c) * 224 + u * 32 + h]));
    }
  } else {
    int w = tid & 31, h0 = tid >> 5;
    #pragma unroll
    for (int r = 0; r < 4; ++r) {
      int h = h0 + 8 * r;
      mx = fmaxf(mx, b2f(x3[((896 + b * 224 + u * 32 + h) * 32 + c) * 224 + vq * 32 + w]));
    }
  }
  #pragma unroll
  for (int m = 32; m >= 1; m >>= 1) mx = fmaxf(mx, __shfl_xor(mx, m));
  if ((tid & 63) == 0) red[tid >> 6] = mx;
  __syncthreads();
  if (tid == 0)
    gmax[t * 64 + c64] = fmaxf(fmaxf(red[0], red[1]), fmaxf(red[2], red[3]));
}

// ---------------- K9b: FC gate ----------------
__global__ __launch_bounds__(256) void k9_fc(const float* __restrict__ gmax,
    const float* __restrict__ f1, const float* __restrict__ f2, float* __restrict__ gate)
{
  int t = blockIdx.x * 256 + threadIdx.x;
  if (t >= 196) return;
  float g1[8];
  #pragma unroll
  for (int o = 0; o < 8; ++o) {
    float a = 0.f;
    #pragma unroll
    for (int c2 = 0; c2 < 64; ++c2) a += f1[o * 64 + c2] * gmax[t * 64 + c2];
    g1[o] = (a >= 0.f) ? a : 0.1f * a;
  }
  #pragma unroll
  for (int c2 = 0; c2 < 32; ++c2) {
    float a = 0.f;
    #pragma unroll
    for (int o = 0; o < 8; ++o) a += f2[c2 * 8 + o] * g1[o];
    gate[t * 32 + c2] = 1.f / (1.f + expf(-a));
  }
}

// ---------------- K9c: gated combine -> out[t][c][h][w] f32 ----------------
__global__ __launch_bounds__(256) void k9_final(const u16* __restrict__ x3,
    const float* __restrict__ gate, float* __restrict__ out)
{
  __shared__ float o1s[32][33];
  const int bid = blockIdx.x;   // t*32 + c
  const int c = bid & 31;
  const int t = bid >> 5;
  const int b = t / 49; const int uv = t % 49; const int u = uv / 7; const int vq = uv % 7;
  const int tid = threadIdx.x;
  const float g = gate[t * 32 + c];
  #pragma unroll
  for (int r = 0; r < 4; ++r) {
    int h = tid & 31; int w = (tid >> 5) + 8 * r;
    o1s[w][h] = b2f(x3[((b * 224 + vq * 32 + w) * 32 + c) * 224 + u * 32 + h]);
  }
  __syncthreads();
  #pragma unroll
  for (int r = 0; r < 4; ++r) {
    int w = tid & 31; int h = (tid >> 5) + 8 * r;
    float o2 = b2f(x3[((896 + b * 224 + u * 32 + h) * 32 + c) * 224 + vq * 32 + w]);
    float o1 = o1s[w][h];
    out[(t * 32 + c) * 1024 + h * 32 + w] = o1 * g + o2 * (1.f - g);
  }
}

extern "C" void kernel_launch(void* const* d_in, const int* in_sizes, int n_in,
                              void* d_out, int out_size, void* d_ws, size_t ws_size,
                              hipStream_t stream)
{
  const float* xlf    = (const float*)d_in[0];
  const float* h_lin  = (const float*)d_in[1];
  const float* h_temp = (const float*)d_in[2];
  const float* h_g1   = (const float*)d_in[3];
  const float* h_b1   = (const float*)d_in[4];
  const float* h_qkv  = (const float*)d_in[5];
  const float* h_qdw  = (const float*)d_in[6];
  const float* h_proj = (const float*)d_in[7];
  const float* h_ca   = (const float*)d_in[8];
  const float* h_ge   = (const float*)d_in[9];
  const float* h_be   = (const float*)d_in[10];
  const float* h_pin  = (const float*)d_in[11];
  const float* h_dw   = (const float*)d_in[12];
  const float* h_po   = (const float*)d_in[13];
  const float* v_lin  = (const float*)d_in[14];
  const float* v_temp = (const float*)d_in[15];
  const float* v_g1   = (const float*)d_in[16];
  const float* v_b1   = (const float*)d_in[17];
  const float* v_qkv  = (const float*)d_in[18];
  const float* v_qdw  = (const float*)d_in[19];
  const float* v_proj = (const float*)d_in[20];
  const float* v_ca   = (const float*)d_in[21];
  const float* v_ge   = (const float*)d_in[22];
  const float* v_be   = (const float*)d_in[23];
  const float* v_pin  = (const float*)d_in[24];
  const float* v_dw   = (const float*)d_in[25];
  const float* v_po   = (const float*)d_in[26];
  const float* f1     = (const float*)d_in[27];
  const float* f2     = (const float*)d_in[28];

  char* w = (char*)d_ws;
  u16*   x2    = (u16*)  (w + 0);          // 25,690,112 B
  float* xq    = (float*)(w + 25690112);   //    917,504 B (aliased by ao after K3)
  float* qkvp  = (float*)(w + 26607616);   //  2,752,512 B (aliased by qkvn after K4)
  float* qkvd  = (float*)(w + 29360128);   //  2,752,512 B
  float* gmax  = (float*)(w + 32112640);   //     50,176 B
  float* gate  = (float*)(w + 32162816);   //     25,088 B
  float* poT   = (float*)(w + 32187904);   //     43,520 B
  u16*   linwB = (u16*)  (w + 32231424);   //  3,670,016 B (k_wprep -> k1)
  float* qkvn = qkvp;                      // K5 writes (qkvp dead)
  float* ao   = xq;                        // K6 writes (xq dead)
  // total ws used: 35,901,440 B (~34.2 MB)

  k0_zero  <<<896, 256, 0, stream>>>(xq);
  k_wprep  <<<1792, 256, 0, stream>>>(h_lin, v_lin, linwB);
  k8_prep  <<<22, 256, 0, stream>>>(h_po, v_po, poT);
  k1_mfma  <<<dim3(16, 4, 8), 256, 0, stream>>>(xlf, linwB, xq);
  k3_lnqkv <<<dim3(28, 4, 2), 256, 0, stream>>>(xq, h_g1, h_b1, v_g1, v_b1, h_qkv, v_qkv, qkvp);
  k4_dw    <<<2688, 256, 0, stream>>>(qkvp, h_qdw, v_qdw, qkvd);
  k5_heads <<<96, 256, 0, stream>>>(qkvd, qkvn);
  k6_attn  <<<dim3(28, 4, 2), 256, 0, stream>>>(qkvn, h_temp, v_temp, h_ca, v_ca, ao);
  k7_proj  <<<dim3(128, 4, 2), 256, 0, stream>>>(ao, h_proj, v_proj, xlf, x2);
  k8_mlp   <<<dim3(896, 2), 256, 0, stream>>>(x2, h_ge, h_be, v_ge, v_be,
                                              h_pin, v_pin, h_dw, v_dw, poT);
  k9_pool  <<<12544, 256, 0, stream>>>(x2, gmax);
  k9_fc    <<<1, 256, 0, stream>>>(gmax, f1, f2, gate);
  k9_final <<<6272, 256, 0, stream>>>(x2, gate, (float*)d_out);
}

// Round 11
// 692.430 us; speedup vs baseline: 1.2451x; 1.1798x over previous
//
#include <hip/hip_runtime.h>
#include <math.h>

typedef unsigned short u16;
typedef unsigned int   u32;
typedef __attribute__((ext_vector_type(8))) short short8;
typedef __attribute__((ext_vector_type(4))) float float4v;

#define DI __device__ __forceinline__

DI float b2f(u16 v){ return __uint_as_float(((u32)v) << 16); }
DI u16 f2b(float f){
  u32 u = __float_as_uint(f);
  u32 r = (u + 0x7fffu + ((u >> 16) & 1u)) >> 16;
  return (u16)r;
}
DI float gelu_exact(float x){ return x * 0.5f * (1.0f + erff(x * 0.70710678118654752f)); }

// Shapes: Bb=4, A=7, C=32, H=W=32, E=128, HEADS=4, d=32, L=N=224, K_tok=7168, HID=85
// x_lf flat: [196][32][32][32] f32, img=(b*49+u*7+v), elem = img*32768 + c*1024 + h*32 + w
// branch 0 (h): token l=(u,h), reduce k=(c, n=(v,w))
// branch 1 (v): token l=(v,w), reduce k=(c, n=(u,h))
//
// Verified MFMA recipe (k1_mfma, R10 pass): mfma_f32_16x16x32_bf16 with BOTH operands
// loaded as [row][k], row=lane&15, k=quad*8+j (8 contiguous bf16 = one ds/global b128);
// D[m][n]: m = quad*4+reg (from A rows), n = lane&15 (from B rows).

// ---------------- K0: zero xq ----------------
__global__ __launch_bounds__(256) void k0_zero(float* __restrict__ xq)
{
  int idx = blockIdx.x * 256 + threadIdx.x;
  if (idx < 229376) xq[idx] = 0.f;
}

// ---------------- k_wprep: lin_w f32 -> bf16 [br][128][7168] ----------------
__global__ __launch_bounds__(256) void k_wprep(const float* __restrict__ w0,
    const float* __restrict__ w1, u16* __restrict__ linwB)
{
  int base = blockIdx.x * 1024 + threadIdx.x;   // 1,835,008 total
  #pragma unroll
  for (int r = 0; r < 4; ++r) {
    int i = base + 256 * r;
    if (i < 1835008) {
      const float* src = (i < 917504) ? w0 : w1;
      linwB[i] = f2b(src[i % 917504]);
    }
  }
}

// ---------------- k8w_prep: pin -> pinB bf16 [br][2][96][32] (zero-pad r>=85),
//                  po -> poB bf16 [br][32][96] (zero-pad r>=85) ----------------
__global__ __launch_bounds__(256) void k8w_prep(const float* __restrict__ pin0,
    const float* __restrict__ pin1, const float* __restrict__ po0,
    const float* __restrict__ po1, u16* __restrict__ pinB, u16* __restrict__ poB)
{
  int idx = blockIdx.x * 256 + threadIdx.x;   // 18432 total
  if (idx < 12288) {
    int cc = idx & 31;
    int r = (idx >> 5) % 96;
    int hb = (idx >> 5) / 96;       // br*2+half
    int br = hb >> 1, half = hb & 1;
    const float* p = br ? pin1 : pin0;
    pinB[idx] = (r < 85) ? f2b(p[(half * 85 + r) * 32 + cc]) : (u16)0;
  } else if (idx < 18432) {
    int j = idx - 12288;
    int r = j % 96;
    int t = j / 96;                 // br*32+cc
    int br = t >> 5, cc = t & 31;
    const float* p = br ? po1 : po0;
    poB[j] = (r < 85) ? f2b(p[cc * 85 + r]) : (u16)0;
  }
}

// ---------------- K1 (MFMA): token GEMM, atomic accumulate into xq[bb][e][l] ----------------
__global__ __launch_bounds__(256) void k1_mfma(const float* __restrict__ xlf,
    const u16* __restrict__ linwB, float* __restrict__ xq)
{
  __shared__ u16 Asb[64][40];
  __shared__ u16 Wsb[128][40];
  const int ks   = blockIdx.x;   // 0..15
  const int mblk = blockIdx.y;   // 0..3
  const int bb   = blockIdx.z;   // br*4+b
  const int br = bb >> 2, b = bb & 3;
  const int tid = threadIdx.x;
  const int wid = tid >> 6, lane = tid & 63;
  const int quad = lane >> 4, r16 = lane & 15;
  const int m0s = mblk * 64 + wid * 16;
  const bool active = (m0s < 224);
  const u16* wsrc = linwB + br * 917504;

  float4v acc[8];
  #pragma unroll
  for (int nt = 0; nt < 8; ++nt) acc[nt] = (float4v){0.f, 0.f, 0.f, 0.f};

  #pragma unroll 1
  for (int step = 0; step < 14; ++step) {
    const int k0 = ks * 448 + step * 32;
    const int c   = k0 / 224;
    const int rem = k0 % 224;
    #pragma unroll
    for (int r = 0; r < 8; ++r) {
      int idx = tid + 256 * r;
      int ml = idx >> 5, kl = idx & 31;
      int l = mblk * 64 + ml;
      float val = 0.f;
      if (l < 224) {
        int u, h, v2, w2;
        if (br == 0) { u = l >> 5; h = l & 31; v2 = rem >> 5; w2 = kl; }
        else         { v2 = l >> 5; w2 = l & 31; u = rem >> 5; h = kl; }
        val = xlf[(b * 49 + u * 7 + v2) * 32768 + c * 1024 + h * 32 + w2];
      }
      Asb[ml][kl] = f2b(val);
    }
    #pragma unroll
    for (int r = 0; r < 16; ++r) {
      int idx = tid + 256 * r;
      int e = idx >> 5, kl = idx & 31;
      Wsb[e][kl] = wsrc[e * 7168 + k0 + kl];
    }
    __syncthreads();
    if (active) {
      short8 af = *(const short8*)&Asb[wid * 16 + r16][quad * 8];
      #pragma unroll
      for (int nt = 0; nt < 8; ++nt) {
        short8 bf = *(const short8*)&Wsb[nt * 16 + r16][quad * 8];
        acc[nt] = __builtin_amdgcn_mfma_f32_16x16x32_bf16(af, bf, acc[nt], 0, 0, 0);
      }
    }
    __syncthreads();
  }
  if (active) {
    #pragma unroll
    for (int nt = 0; nt < 8; ++nt) {
      int e = nt * 16 + r16;
      #pragma unroll
      for (int reg = 0; reg < 4; ++reg) {
        int tok = m0s + quad * 4 + reg;
        atomicAdd(&xq[(bb * 128 + e) * 224 + tok], acc[nt][reg]);
      }
    }
  }
}

// ---------------- K3: LN(E) + qkv 1x1 -> qkvp[br][b][384][224] ----------------
__global__ __launch_bounds__(256) void k3_lnqkv(const float* __restrict__ xq,
    const float* __restrict__ g0, const float* __restrict__ b0,
    const float* __restrict__ g1, const float* __restrict__ b1,
    const float* __restrict__ qw0, const float* __restrict__ qw1,
    float* __restrict__ qkvp)
{
  __shared__ float xn[8][129];
  const int lc = blockIdx.x;     // 0..27
  const int b = blockIdx.y, br = blockIdx.z;
  const float* lg = br ? g1 : g0;
  const float* lb = br ? b1 : b0;
  const float* qw = br ? qw1 : qw0;
  const int tid = threadIdx.x;
  const int tl = tid >> 5, lane = tid & 31;
  const int l = lc * 8 + tl;
  const float* xp = xq + ((br * 4 + b) * 128) * 224 + l;
  float v[4]; float s = 0.f, s2 = 0.f;
  #pragma unroll
  for (int i = 0; i < 4; ++i) { v[i] = xp[(lane + 32 * i) * 224]; s += v[i]; s2 += v[i] * v[i]; }
  #pragma unroll
  for (int m = 16; m >= 1; m >>= 1) { s += __shfl_xor(s, m); s2 += __shfl_xor(s2, m); }
  float mean = s * (1.f / 128.f);
  float var  = s2 * (1.f / 128.f) - mean * mean;
  float rs   = rsqrtf(fmaxf(var, 0.f) + 1e-6f);
  #pragma unroll
  for (int i = 0; i < 4; ++i) {
    int c = lane + 32 * i;
    xn[tl][c] = (v[i] - mean) * rs * lg[c] + lb[c];
  }
  __syncthreads();
  for (int jj = 0; jj < 12; ++jj) {
    int idx = tid + 256 * jj;
    int o = idx >> 3, li = idx & 7;
    const float* wr = qw + o * 128;
    float a = 0.f;
    for (int c2 = 0; c2 < 128; ++c2) a += wr[c2] * xn[li][c2];
    qkvp[((br * 4 + b) * 384 + o) * 224 + lc * 8 + li] = a;
  }
}

// ---------------- K4: depthwise 3x3 over (7,32) ----------------
__global__ __launch_bounds__(256) void k4_dw(const float* __restrict__ qkvp,
    const float* __restrict__ dw0, const float* __restrict__ dw1, float* __restrict__ qkvd)
{
  int idx = blockIdx.x * 256 + threadIdx.x;  // 688128
  int l = idx % 224; int r0 = idx / 224;     // r0 = (br*4+b)*384 + o
  int o = r0 % 384;
  int br = (r0 / 384) >> 2;
  const float* dww = (br ? dw1 : dw0) + o * 9;
  int v = l >> 5, w = l & 31;
  const float* src = qkvp + r0 * 224;
  float acc = 0.f;
  #pragma unroll
  for (int dy = -1; dy <= 1; ++dy) {
    int vv = v + dy; if (vv < 0 || vv > 6) continue;
    #pragma unroll
    for (int dx = -1; dx <= 1; ++dx) {
      int ww = w + dx; if (ww < 0 || ww > 31) continue;
      acc += src[vv * 32 + ww] * dww[(dy + 1) * 3 + (dx + 1)];
    }
  }
  qkvd[idx] = acc;
}

// ---------------- K5: head split + l2norm(q,k) -> qkvn[bb][sel][h][l][d] ----------------
__global__ __launch_bounds__(256) void k5_heads(const float* __restrict__ qkvd, float* __restrict__ qkvn)
{
  __shared__ float ts[32][225];
  __shared__ float scs[224];
  const int bid = blockIdx.x;          // bb*12 + sel*4 + h, 96 blocks
  const int h = bid & 3;
  const int sel = (bid >> 2) % 3;
  const int bb = bid / 12;
  const int tid = threadIdx.x;
  const float* src = qkvd + (bb * 384 + sel * 128 + h * 32) * 224;
  for (int r = 0; r < 28; ++r) {
    int idx = tid + 256 * r;
    int d = idx / 224, l = idx % 224;
    ts[d][l] = src[d * 224 + l];
  }
  __syncthreads();
  if (tid < 224) {
    float ss = 0.f;
    for (int d = 0; d < 32; ++d) { float x = ts[d][tid]; ss += x * x; }
    scs[tid] = (sel < 2) ? (1.0f / fmaxf(sqrtf(ss), 1e-12f)) : 1.0f;
  }
  __syncthreads();
  float* dst = qkvn + ((bb * 3 + sel) * 4 + h) * 7168;
  for (int r = 0; r < 28; ++r) {
    int idx = tid + 256 * r;
    int d = idx & 31, l = idx >> 5;
    dst[l * 32 + d] = ts[d][l] * scs[l];
  }
}

// ---------------- K6: fused attention -> ao[bb][e][l] ----------------
__global__ __launch_bounds__(256) void k6_attn(const float* __restrict__ qkvn,
    const float* __restrict__ tmp0, const float* __restrict__ tmp1,
    const float* __restrict__ ca0,  const float* __restrict__ ca1,
    float* __restrict__ ao)
{
  __shared__ float qs[32][33];      // (h*8+i, d)
  __shared__ float ks[128][33];     // (h*32+jj, d)
  __shared__ float sS[32 * 228];    // (h*8+i)*228 + j
  __shared__ float mxs[32], rss[32];
  __shared__ float caf[32], tpf[4];
  const int it = blockIdx.x;        // 0..27 i-tile
  const int b = blockIdx.y, br = blockIdx.z;
  const int bb = br * 4 + b;
  const int tid = threadIdx.x;
  const float* tw = br ? tmp1 : tmp0;
  const float* cw = br ? ca1 : ca0;
  if (tid < 32) caf[tid] = cw[tid];
  if (tid < 4)  tpf[tid] = tw[tid];
  const int i0 = it * 8;
  const float* qb = qkvn + (bb * 3 + 0) * 4 * 7168;
  const float* kb = qkvn + (bb * 3 + 1) * 4 * 7168;
  const float* vb = qkvn + (bb * 3 + 2) * 4 * 7168;
  #pragma unroll
  for (int r = 0; r < 4; ++r) {
    int idx = tid + 256 * r;
    int d = idx & 31, i = (idx >> 5) & 7, h = idx >> 8;
    qs[h * 8 + i][d] = qb[h * 7168 + (i0 + i) * 32 + d];
  }
  const int hC = tid >> 6, iC = (tid >> 3) & 7, jq = tid & 7;
  for (int jt = 0; jt < 7; ++jt) {
    __syncthreads();
    #pragma unroll
    for (int r = 0; r < 16; ++r) {
      int idx = tid + 256 * r;
      int d = idx & 31, jj = (idx >> 5) & 31, h = idx >> 10;
      ks[h * 32 + jj][d] = kb[h * 7168 + (jt * 32 + jj) * 32 + d];
    }
    __syncthreads();
    float a4[4] = {0.f, 0.f, 0.f, 0.f};
    for (int d = 0; d < 32; ++d) {
      float qv = qs[hC * 8 + iC][d];
      #pragma unroll
      for (int r = 0; r < 4; ++r) a4[r] += qv * ks[hC * 32 + jq + 8 * r][d];
    }
    #pragma unroll
    for (int r = 0; r < 4; ++r)
      sS[(hC * 8 + iC) * 228 + jt * 32 + jq + 8 * r] = a4[r] * tpf[hC];
  }
  __syncthreads();
  { // softmax stats per row
    int p = tid & 7, row = tid >> 3;
    float mx = -1e30f;
    for (int q = 0; q < 28; ++q) mx = fmaxf(mx, sS[row * 228 + p + 8 * q]);
    #pragma unroll
    for (int m = 4; m >= 1; m >>= 1) mx = fmaxf(mx, __shfl_xor(mx, m));
    float es = 0.f;
    for (int q = 0; q < 28; ++q) es += expf(sS[row * 228 + p + 8 * q] - mx);
    #pragma unroll
    for (int m = 4; m >= 1; m >>= 1) es += __shfl_xor(es, m);
    if (p == 0) { mxs[row] = mx; rss[row] = 1.0f / es; }
  }
  __syncthreads();
  // attn = softmax*(1+scale)+shift, in place over sS
  for (int q = 0; q < 7; ++q) {
    int pr = tid + 256 * q;
    int i = pr / 224, j = pr % 224;
    float a1[4];
    #pragma unroll
    for (int hh = 0; hh < 4; ++hh) {
      float sv = sS[(hh * 8 + i) * 228 + j];
      float z = fmaxf(sv, 0.f); float z2 = z * z;
      a1[hh] = gelu_exact(z2) * z2;
    }
    #pragma unroll
    for (int hh = 0; hh < 4; ++hh) {
      float sc = 0.f, sh = 0.f;
      #pragma unroll
      for (int k2 = 0; k2 < 4; ++k2) { sc += caf[hh * 4 + k2] * a1[k2]; sh += caf[(hh + 4) * 4 + k2] * a1[k2]; }
      int row = hh * 8 + i;
      float at = expf(sS[row * 228 + j] - mxs[row]) * rss[row];
      sS[row * 228 + j] = at * (1.f + sc) + sh;
    }
  }
  __syncthreads();
  { // PV
    int d = tid & 31, rg = tid >> 5;
    float acc[4] = {0.f, 0.f, 0.f, 0.f};
    for (int j = 0; j < 224; ++j) {
      #pragma unroll
      for (int hh = 0; hh < 4; ++hh)
        acc[hh] += sS[(hh * 8 + rg) * 228 + j] * vb[hh * 7168 + j * 32 + d];
    }
    #pragma unroll
    for (int hh = 0; hh < 4; ++hh)
      ao[(bb * 128 + hh * 32 + d) * 224 + i0 + rg] = acc[hh];
  }
}

// ---------------- K7: proj GEMM + x_res residual -> x2[br][bn][c][l] (bf16) ----------------
__global__ __launch_bounds__(256) void k7_proj(const float* __restrict__ ao,
    const float* __restrict__ pw0, const float* __restrict__ pw1,
    const float* __restrict__ xlf, u16* __restrict__ x2)
{
  __shared__ float Xs[32][225];
  __shared__ float Ws[56][33];
  const int tt = blockIdx.x;          // 0..127: c = tt>>2, n0 = (tt&3)*56
  const int b = blockIdx.y, br = blockIdx.z;
  const int c = tt >> 2;
  const int n0 = (tt & 3) * 56;
  const float* pw = br ? pw1 : pw0;
  const int tid = threadIdx.x;
  const int tl = tid & 31, tn = tid >> 5;
  float acc[7][7] = {};
  const float* xsrc = ao + (br * 4 + b) * 128 * 224;
  for (int ec = 0; ec < 4; ++ec) {
    __syncthreads();
    for (int r = 0; r < 28; ++r) {
      int idx = tid + 256 * r;
      int ee = idx / 224, l = idx % 224;
      Xs[ee][l] = xsrc[(ec * 32 + ee) * 224 + l];
    }
    #pragma unroll
    for (int r = 0; r < 7; ++r) {
      int idx = tid + 256 * r;
      int nn = idx >> 5, ee = idx & 31;
      Ws[nn][ee] = pw[(c * 224 + n0 + nn) * 128 + ec * 32 + ee];
    }
    __syncthreads();
    for (int ee = 0; ee < 32; ++ee) {
      float xv[7], wv[7];
      #pragma unroll
      for (int q = 0; q < 7; ++q) xv[q] = Xs[ee][tl + 32 * q];
      #pragma unroll
      for (int p = 0; p < 7; ++p) wv[p] = Ws[tn + 8 * p][ee];
      #pragma unroll
      for (int p = 0; p < 7; ++p)
        #pragma unroll
        for (int q = 0; q < 7; ++q) acc[p][q] += wv[p] * xv[q];
    }
  }
  #pragma unroll
  for (int p = 0; p < 7; ++p) {
    int n = n0 + tn + 8 * p;
    #pragma unroll
    for (int q = 0; q < 7; ++q) {
      int l = tl + 32 * q;
      int img, off;
      if (br == 0) { img = b * 49 + (l >> 5) * 7 + (n >> 5); off = c * 1024 + (l & 31) * 32 + (n & 31); }
      else         { img = b * 49 + (n >> 5) * 7 + (l >> 5); off = c * 1024 + (n & 31) * 32 + (l & 31); }
      float res = xlf[img * 32768 + off];
      x2[((br * 896 + b * 224 + n) * 32 + c) * 224 + l] = f2b(acc[p][q] + res);
    }
  }
}

// ---------------- K8 (MFMA): LN(C)+pin+dw3x3+gelu gate+pout+residual, in place on x2 ----------------
// pin GEMM (M=170 r-rows, N=224 tok, K=32 ch) and pout GEMM (M=32 ch, N=224, K=85->96)
// on matrix cores; dw 3x3 stencil in SIMT between them. r padded to 96 (zero weights ->
// g=0 -> no pout contribution). 3 K-super-chunks of 32 (2 pin sub-chunks of 16 each).
__global__ __launch_bounds__(256) void k8_mfma(u16* x2,
    const float* __restrict__ lg0, const float* __restrict__ lb0,
    const float* __restrict__ lg1, const float* __restrict__ lb1,
    const float* __restrict__ dwa0, const float* __restrict__ dwa1,
    const u16* __restrict__ pinB, const u16* __restrict__ poB)
{
  __shared__ u16 xnb[224][40];   // LN'd x, B-layout (row=tok, k=ch)        17,920 B
  __shared__ u16 t1s[16][232];   // pin t1 sub-chunk                          7,424 B
  __shared__ u16 tgs[16][232];   // pin tg sub-chunk                          7,424 B
  __shared__ u16 gsb[224][40];   // gated g, B-layout (row=tok, k=r-super)  17,920 B
  const int img = blockIdx.x;    // 0..895
  const int br  = blockIdx.y;
  const float* lg  = br ? lg1 : lg0;
  const float* lb  = br ? lb1 : lb0;
  const float* dww = br ? dwa1 : dwa0;
  const u16* pinBr = pinB + br * 2 * 96 * 32;
  const u16* poBr  = poB + br * 32 * 96;
  const int tid = threadIdx.x;
  const int wid = tid >> 6, lane = tid & 63;
  const int quad = lane >> 4, r16 = lane & 15;
  u16* src = x2 + (br * 896 + img) * 7168;

  // phase 0: LN(C) per token -> xnb bf16
  if (tid < 224) {
    float xr[32];
    #pragma unroll
    for (int cc = 0; cc < 32; ++cc) xr[cc] = b2f(src[cc * 224 + tid]);
    float s = 0.f, s2 = 0.f;
    #pragma unroll
    for (int cc = 0; cc < 32; ++cc) { s += xr[cc]; s2 += xr[cc] * xr[cc]; }
    float mean = s * (1.f / 32.f);
    float var  = s2 * (1.f / 32.f) - mean * mean;
    float rs   = rsqrtf(fmaxf(var, 0.f) + 1e-6f);
    #pragma unroll
    for (int cc = 0; cc < 32; ++cc)
      xnb[tid][cc] = f2b((xr[cc] - mean) * rs * lg[cc] + lb[cc]);
  }
  __syncthreads();

  float4v acc[7];
  #pragma unroll
  for (int i = 0; i < 7; ++i) acc[i] = (float4v){0.f, 0.f, 0.f, 0.f};

  #pragma unroll 1
  for (int s = 0; s < 3; ++s) {
    #pragma unroll 1
    for (int hh = 0; hh < 2; ++hh) {
      const int r0 = s * 32 + hh * 16;
      // pin MFMA: 28 tiles (2 M-halves x 14 N), 7 per wave
      #pragma unroll
      for (int i = 0; i < 7; ++i) {
        int t = wid + 4 * i;
        int m = t / 14, n = t - m * 14;
        short8 af = *(const short8*)&pinBr[((m * 96 + r0 + r16) << 5) + quad * 8];
        short8 bf = *(const short8*)&xnb[n * 16 + r16][quad * 8];
        float4v d = __builtin_amdgcn_mfma_f32_16x16x32_bf16(af, bf,
                     (float4v){0.f, 0.f, 0.f, 0.f}, 0, 0, 0);
        u16* dst = m ? &tgs[0][0] : &t1s[0][0];
        #pragma unroll
        for (int reg = 0; reg < 4; ++reg)
          dst[(quad * 4 + reg) * 232 + n * 16 + r16] = f2b(d[reg]);
      }
      __syncthreads();
      // dw 3x3 + gelu gate -> gsb[:, hh*16 + r_loc]
      #pragma unroll 1
      for (int i = 0; i < 14; ++i) {
        int item = tid + 256 * i;          // 16*224
        int rl = item / 224, l = item - rl * 224;
        int r = r0 + rl;
        float g = 0.f;
        if (r < 85) {
          const float* w1 = dww + r * 9;
          const float* w2 = dww + (85 + r) * 9;
          int v = l >> 5, wq = l & 31;
          float d1 = 0.f, d2 = 0.f;
          #pragma unroll
          for (int dy = -1; dy <= 1; ++dy) {
            int vv = v + dy; if (vv < 0 || vv > 6) continue;
            #pragma unroll
            for (int dx = -1; dx <= 1; ++dx) {
              int ww = wq + dx; if (ww < 0 || ww > 31) continue;
              int li = vv * 32 + ww; int wi = (dy + 1) * 3 + dx + 1;
              d1 += b2f(t1s[rl][li]) * w1[wi];
              d2 += b2f(tgs[rl][li]) * w2[wi];
            }
          }
          g = gelu_exact(d1) * d2;
        }
        gsb[l][hh * 16 + rl] = f2b(g);
      }
      __syncthreads();
    }
    // pout MFMA: 28 tiles (2 cc-tiles x 14 N), K=32 (this super), accumulate
    #pragma unroll
    for (int i = 0; i < 7; ++i) {
      int u = wid + 4 * i;
      int mt = u / 14, n = u - mt * 14;
      short8 af = *(const short8*)&poBr[(mt * 16 + r16) * 96 + s * 32 + quad * 8];
      short8 bf = *(const short8*)&gsb[n * 16 + r16][quad * 8];
      acc[i] = __builtin_amdgcn_mfma_f32_16x16x32_bf16(af, bf, acc[i], 0, 0, 0);
    }
    // no barrier needed: next super's pin barrier orders gsb reads before dw rewrites
  }
  // epilogue: residual RMW
  #pragma unroll
  for (int i = 0; i < 7; ++i) {
    int u = wid + 4 * i;
    int mt = u / 14, n = u - mt * 14;
    #pragma unroll
    for (int reg = 0; reg < 4; ++reg) {
      int cc = mt * 16 + quad * 4 + reg;
      int tok = n * 16 + r16;
      int o = cc * 224 + tok;
      src[o] = f2b(b2f(src[o]) + acc[i][reg]);
    }
  }
}

// ---------------- K9a: adaptive max pool per (t, c64) ----------------
__global__ __launch_bounds__(256) void k9_pool(const u16* __restrict__ x3, float* __restrict__ gmax)
{
  __shared__ float red[4];
  const int bid = blockIdx.x;      // t*64 + c64
  const int c64 = bid & 63;
  const int t = bid >> 6;
  const int c = c64 & 31, which = c64 >> 5;
  const int b = t / 49; const int uv = t % 49; const int u = uv / 7; const int vq = uv % 7;
  const int tid = threadIdx.x;
  float mx = -1e30f;
  if (which == 0) {
    int h = tid & 31, w0 = tid >> 5;
    #pragma unroll
    for (int r = 0; r < 4; ++r) {
      int w = w0 + 8 * r;
      mx = fmaxf(mx, b2f(x3[((b * 224 + vq * 32 + w) * 32 + c) * 224 + u * 32 + h]));
    }
  } else {
    int w = tid & 31, h0 = tid >> 5;
    #pragma unroll
    for (int r = 0; r < 4; ++r) {
      int h = h0 + 8 * r;
      mx = fmaxf(mx, b2f(x3[((896 + b * 224 + u * 32 + h) * 32 + c) * 224 + vq * 32 + w]));
    }
  }
  #pragma unroll
  for (int m = 32; m >= 1; m >>= 1) mx = fmaxf(mx, __shfl_xor(mx, m));
  if ((tid & 63) == 0) red[tid >> 6] = mx;
  __syncthreads();
  if (tid == 0)
    gmax[t * 64 + c64] = fmaxf(fmaxf(red[0], red[1]), fmaxf(red[2], red[3]));
}

// ---------------- K9b: FC gate ----------------
__global__ __launch_bounds__(256) void k9_fc(const float* __restrict__ gmax,
    const float* __restrict__ f1, const float* __restrict__ f2, float* __restrict__ gate)
{
  int t = blockIdx.x * 256 + threadIdx.x;
  if (t >= 196) return;
  float g1[8];
  #pragma unroll
  for (int o = 0; o < 8; ++o) {
    float a = 0.f;
    #pragma unroll
    for (int c2 = 0; c2 < 64; ++c2) a += f1[o * 64 + c2] * gmax[t * 64 + c2];
    g1[o] = (a >= 0.f) ? a : 0.1f * a;
  }
  #pragma unroll
  for (int c2 = 0; c2 < 32; ++c2) {
    float a = 0.f;
    #pragma unroll
    for (int o = 0; o < 8; ++o) a += f2[c2 * 8 + o] * g1[o];
    gate[t * 32 + c2] = 1.f / (1.f + expf(-a));
  }
}

// ---------------- K9c: gated combine -> out[t][c][h][w] f32 ----------------
__global__ __launch_bounds__(256) void k9_final(const u16* __restrict__ x3,
    const float* __restrict__ gate, float* __restrict__ out)
{
  __shared__ float o1s[32][33];
  const int bid = blockIdx.x;   // t*32 + c
  const int c = bid & 31;
  const int t = bid >> 5;
  const int b = t / 49; const int uv = t % 49; const int u = uv / 7; const int vq = uv % 7;
  const int tid = threadIdx.x;
  const float g = gate[t * 32 + c];
  #pragma unroll
  for (int r = 0; r < 4; ++r) {
    int h = tid & 31; int w = (tid >> 5) + 8 * r;
    o1s[w][h] = b2f(x3[((b * 224 + vq * 32 + w) * 32 + c) * 224 + u * 32 + h]);
  }
  __syncthreads();
  #pragma unroll
  for (int r = 0; r < 4; ++r) {
    int w = tid & 31; int h = (tid >> 5) + 8 * r;
    float o2 = b2f(x3[((896 + b * 224 + u * 32 + h) * 32 + c) * 224 + vq * 32 + w]);
    float o1 = o1s[w][h];
    out[(t * 32 + c) * 1024 + h * 32 + w] = o1 * g + o2 * (1.f - g);
  }
}

extern "C" void kernel_launch(void* const* d_in, const int* in_sizes, int n_in,
                              void* d_out, int out_size, void* d_ws, size_t ws_size,
                              hipStream_t stream)
{
  const float* xlf    = (const float*)d_in[0];
  const float* h_lin  = (const float*)d_in[1];
  const float* h_temp = (const float*)d_in[2];
  const float* h_g1   = (const float*)d_in[3];
  const float* h_b1   = (const float*)d_in[4];
  const float* h_qkv  = (const float*)d_in[5];
  const float* h_qdw  = (const float*)d_in[6];
  const float* h_proj = (const float*)d_in[7];
  const float* h_ca   = (const float*)d_in[8];
  const float* h_ge   = (const float*)d_in[9];
  const float* h_be   = (const float*)d_in[10];
  const float* h_pin  = (const float*)d_in[11];
  const float* h_dw   = (const float*)d_in[12];
  const float* h_po   = (const float*)d_in[13];
  const float* v_lin  = (const float*)d_in[14];
  const float* v_temp = (const float*)d_in[15];
  const float* v_g1   = (const float*)d_in[16];
  const float* v_b1   = (const float*)d_in[17];
  const float* v_qkv  = (const float*)d_in[18];
  const float* v_qdw  = (const float*)d_in[19];
  const float* v_proj = (const float*)d_in[20];
  const float* v_ca   = (const float*)d_in[21];
  const float* v_ge   = (const float*)d_in[22];
  const float* v_be   = (const float*)d_in[23];
  const float* v_pin  = (const float*)d_in[24];
  const float* v_dw   = (const float*)d_in[25];
  const float* v_po   = (const float*)d_in[26];
  const float* f1     = (const float*)d_in[27];
  const float* f2     = (const float*)d_in[28];

  char* w = (char*)d_ws;
  u16*   x2    = (u16*)  (w + 0);          // 25,690,112 B
  float* xq    = (float*)(w + 25690112);   //    917,504 B (aliased by ao after K3)
  float* qkvp  = (float*)(w + 26607616);   //  2,752,512 B (aliased by qkvn after K4)
  float* qkvd  = (float*)(w + 29360128);   //  2,752,512 B
  float* gmax  = (float*)(w + 32112640);   //     50,176 B
  float* gate  = (float*)(w + 32162816);   //     25,088 B
  u16*   pinB  = (u16*)  (w + 32187904);   //     24,576 B (k8w_prep -> k8)
  u16*   poB   = (u16*)  (w + 32212480);   //     12,288 B (k8w_prep -> k8)
  u16*   linwB = (u16*)  (w + 32224768);   //  3,670,016 B (k_wprep -> k1)
  float* qkvn = qkvp;                      // K5 writes (qkvp dead)
  float* ao   = xq;                        // K6 writes (xq dead)
  // total ws used: 35,894,784 B (~34.2 MB)

  k0_zero  <<<896, 256, 0, stream>>>(xq);
  k_wprep  <<<1792, 256, 0, stream>>>(h_lin, v_lin, linwB);
  k8w_prep <<<72, 256, 0, stream>>>(h_pin, v_pin, h_po, v_po, pinB, poB);
  k1_mfma  <<<dim3(16, 4, 8), 256, 0, stream>>>(xlf, linwB, xq);
  k3_lnqkv <<<dim3(28, 4, 2), 256, 0, stream>>>(xq, h_g1, h_b1, v_g1, v_b1, h_qkv, v_qkv, qkvp);
  k4_dw    <<<2688, 256, 0, stream>>>(qkvp, h_qdw, v_qdw, qkvd);
  k5_heads <<<96, 256, 0, stream>>>(qkvd, qkvn);
  k6_attn  <<<dim3(28, 4, 2), 256, 0, stream>>>(qkvn, h_temp, v_temp, h_ca, v_ca, ao);
  k7_proj  <<<dim3(128, 4, 2), 256, 0, stream>>>(ao, h_proj, v_proj, xlf, x2);
  k8_mfma  <<<dim3(896, 2), 256, 0, stream>>>(x2, h_ge, h_be, v_ge, v_be,
                                              h_dw, v_dw, pinB, poB);
  k9_pool  <<<12544, 256, 0, stream>>>(x2, gmax);
  k9_fc    <<<1, 256, 0, stream>>>(gmax, f1, f2, gate);
  k9_final <<<6272, 256, 0, stream>>>(x2, gate, (float*)d_out);
}